// Round 4
// baseline (1373.037 us; speedup 1.0000x reference)
//
#include <hip/hip_runtime.h>
#include <stdint.h>

typedef unsigned short ushort_t;
typedef __attribute__((ext_vector_type(8))) unsigned short ushort8v;

__device__ __forceinline__ float bf2f(ushort_t u) {
  union { unsigned int i; float f; } v;
  v.i = ((unsigned int)u) << 16;
  return v.f;
}
__device__ __forceinline__ ushort_t f2bf(float f) {
  union { float f; unsigned int i; } v;
  v.f = f;
  unsigned int r = v.i + 0x7FFFu + ((v.i >> 16) & 1u);  // round-to-nearest-even
  return (ushort_t)(r >> 16);
}

// load 8 consecutive elements as fp32
__device__ __forceinline__ void load8(const float* __restrict__ p, float* o) {
  const float4 a = *(const float4*)p;
  const float4 b = *(const float4*)(p + 4);
  o[0] = a.x; o[1] = a.y; o[2] = a.z; o[3] = a.w;
  o[4] = b.x; o[5] = b.y; o[6] = b.z; o[7] = b.w;
}
__device__ __forceinline__ void load8(const ushort_t* __restrict__ p, float* o) {
  const ushort8v v = *(const ushort8v*)p;
#pragma unroll
  for (int j = 0; j < 8; ++j) o[j] = bf2f(v[j]);
}

// store one fp32 value to fp32 or bf16 destination
__device__ __forceinline__ void storeC(float* p, float v) { *p = v; }
__device__ __forceinline__ void storeC(ushort_t* p, float v) { *p = f2bf(v); }

#define BM 64
#define BN 64
#define BK 32

// ---------------------------------------------------------------------------
// Generic GEMM: C[M,N] = A[M,K] * B[K,N] (+bias), fp32 accumulate.
// A: fp32 or bf16; C: fp32 or bf16 (templated); B/bias: fp32.
// BM=BN=64, BK=32, 256 threads, 4x4 register tile. LDS fp32 (+4 pad).
// ---------------------------------------------------------------------------
template <typename TA, typename TC>
__global__ __launch_bounds__(256) void gemm_any(
    const TA* __restrict__ A, const float* __restrict__ B,
    const float* __restrict__ bias, TC* __restrict__ C,
    int M, int N, int K, int has_bias) {
  __shared__ float As[BK][BM + 4];
  __shared__ float Bs[BK][BN + 4];
  const int t = threadIdx.x;
  const int m0 = blockIdx.y * BM;
  const int n0 = blockIdx.x * BN;
  const int tm = (t >> 4) << 2;  // 0..60
  const int tn = (t & 15) << 2;  // 0..60

  float acc[4][4] = {};

  const int am = t >> 2;       // 0..63
  const int ak = (t & 3) * 8;  // 0,8,16,24
  const int bk = t >> 3;       // 0..31
  const int bn = (t & 7) * 8;  // 0..56

  const TA* aptr = A + (size_t)(m0 + am) * K + ak;
  const float* bptr = B + (size_t)bk * N + n0 + bn;

  for (int k0 = 0; k0 < K; k0 += BK) {
    float av[8], bv[8];
    load8(aptr + k0, av);
    load8(bptr + (size_t)k0 * N, bv);
#pragma unroll
    for (int j = 0; j < 8; ++j) As[ak + j][am] = av[j];
#pragma unroll
    for (int j = 0; j < 8; ++j) Bs[bk][bn + j] = bv[j];
    __syncthreads();
#pragma unroll
    for (int k = 0; k < BK; ++k) {
      const float4 a4 = *(const float4*)&As[k][tm];
      const float4 b4 = *(const float4*)&Bs[k][tn];
      const float a[4] = {a4.x, a4.y, a4.z, a4.w};
      const float b[4] = {b4.x, b4.y, b4.z, b4.w};
#pragma unroll
      for (int i = 0; i < 4; ++i)
#pragma unroll
        for (int j = 0; j < 4; ++j) acc[i][j] = fmaf(a[i], b[j], acc[i][j]);
    }
    __syncthreads();
  }

#pragma unroll
  for (int i = 0; i < 4; ++i) {
#pragma unroll
    for (int j = 0; j < 4; ++j) {
      float v = acc[i][j];
      if (has_bias) v += bias[n0 + tn + j];
      storeC(&C[(size_t)(m0 + tm + i) * N + (n0 + tn + j)], v);
    }
  }
}

// ---------------------------------------------------------------------------
// KV conv as GEMM with fused im2col gather, fp32 in, fp32 out.
// C[m=1024][n=1024] = sum_k A[m][k] * Wkv[k][n],  K = 7*7*256 = 12544.
// A[m][k] gathered from x: m = b*64 + ty*8 + tx; k = (dy*7+dx)*256 + c
//   -> x[((b*56 + ty*7+dy)*56 + tx*7+dx)*256 + c]
// ---------------------------------------------------------------------------
__global__ __launch_bounds__(256) void gemm_kv(
    const float* __restrict__ x, const float* __restrict__ B,
    float* __restrict__ C) {
  __shared__ float As[BK][BM + 4];
  __shared__ float Bs[BK][BN + 4];
  const int t = threadIdx.x;
  const int m0 = blockIdx.y * BM;
  const int n0 = blockIdx.x * BN;
  const int tm = (t >> 4) << 2;
  const int tn = (t & 15) << 2;

  float acc[4][4] = {};

  const int am = t >> 2;       // 0..63
  const int ak = (t & 3) * 8;  // 0,8,16,24
  const int bk = t >> 3;       // 0..31
  const int bn = (t & 7) * 8;  // 0..56

  const int m = m0 + am;
  const int b = m >> 6, ty = (m >> 3) & 7, tx = m & 7;
  const int pixbase = b * 3136;  // b*56*56
  const float* bptr = B + (size_t)bk * 1024 + n0 + bn;

  for (int k0 = 0; k0 < 12544; k0 += BK) {
    const int kk = k0 + ak;
    const int patch = kk >> 8;         // 0..48
    const int c = kk & 255;            // 8-aligned
    const int dy = (patch * 37) >> 8;  // exact patch/7 for patch<49
    const int dx = patch - dy * 7;
    const int pix = pixbase + (ty * 7 + dy) * 56 + (tx * 7 + dx);
    float av[8], bv[8];
    load8(x + (size_t)pix * 256 + c, av);
    load8(bptr + (size_t)k0 * 1024, bv);
#pragma unroll
    for (int j = 0; j < 8; ++j) As[ak + j][am] = av[j];
#pragma unroll
    for (int j = 0; j < 8; ++j) Bs[bk][bn + j] = bv[j];
    __syncthreads();
#pragma unroll
    for (int k = 0; k < BK; ++k) {
      const float4 a4 = *(const float4*)&As[k][tm];
      const float4 b4 = *(const float4*)&Bs[k][tn];
      const float a[4] = {a4.x, a4.y, a4.z, a4.w};
      const float bb[4] = {b4.x, b4.y, b4.z, b4.w};
#pragma unroll
      for (int i = 0; i < 4; ++i)
#pragma unroll
        for (int j = 0; j < 4; ++j) acc[i][j] = fmaf(a[i], bb[j], acc[i][j]);
    }
    __syncthreads();
  }

#pragma unroll
  for (int i = 0; i < 4; ++i)
#pragma unroll
    for (int j = 0; j < 4; ++j)
      C[(size_t)(m0 + tm + i) * 1024 + (n0 + tn + j)] = acc[i][j];
}

// ---------------------------------------------------------------------------
// Attention, IN-PLACE on the bf16 q buffer (each element read once then
// written by the same thread). Per (b,h): softmax(Q K^T / 8) V.
// qo: [50176,512] bf16. kv: [1024,1024] fp32.
// ---------------------------------------------------------------------------
__global__ __launch_bounds__(256) void attn_kernel(
    ushort_t* __restrict__ qo, const float* __restrict__ kv) {
  __shared__ float Ks[64][68];   // [key_pos][d]
  __shared__ float VsT[64][68];  // [d][key_pos]
  __shared__ float qs[4][64];
  __shared__ float ps[4][64];
  const int t = threadIdx.x;
  const int bh = blockIdx.y;
  const int b = bh >> 3, h = bh & 7;
  const int chunk = blockIdx.x;  // 0..48, covers 64 query pixels
  const float* kvp = kv + (size_t)(b * 64) * 1024 + h * 64;

  for (int i = t; i < 4096; i += 256) {
    const int pos = i >> 6, d = i & 63;
    Ks[pos][d] = kvp[pos * 1024 + d];
    const int pos2 = i & 63, d2 = i >> 6;
    VsT[d2][pos2] = kvp[pos2 * 1024 + 512 + d2];
  }
  __syncthreads();

  const int w = t >> 6, lane = t & 63;
  for (int it = 0; it < 16; ++it) {
    const int p = chunk * 64 + it * 4 + w;
    const size_t row = (size_t)b * 3136 + p;
    const float qv = bf2f(qo[row * 512 + h * 64 + lane]);
    qs[w][lane] = qv;
    __syncthreads();

    float acc = 0.f;
#pragma unroll
    for (int d4 = 0; d4 < 64; d4 += 4) {
      const float4 q4 = *(const float4*)&qs[w][d4];
      const float4 k4 = *(const float4*)&Ks[lane][d4];
      acc = fmaf(q4.x, k4.x, acc);
      acc = fmaf(q4.y, k4.y, acc);
      acc = fmaf(q4.z, k4.z, acc);
      acc = fmaf(q4.w, k4.w, acc);
    }
    acc *= 0.125f;  // dh^-0.5

    float mx = acc;
#pragma unroll
    for (int off = 32; off >= 1; off >>= 1) mx = fmaxf(mx, __shfl_xor(mx, off));
    const float pe = __expf(acc - mx);
    float s = pe;
#pragma unroll
    for (int off = 32; off >= 1; off >>= 1) s += __shfl_xor(s, off);
    ps[w][lane] = pe;
    __syncthreads();

    float oa = 0.f;
#pragma unroll
    for (int l4 = 0; l4 < 64; l4 += 4) {
      const float4 p4 = *(const float4*)&ps[w][l4];
      const float4 v4 = *(const float4*)&VsT[lane][l4];
      oa = fmaf(p4.x, v4.x, oa);
      oa = fmaf(p4.y, v4.y, oa);
      oa = fmaf(p4.z, v4.z, oa);
      oa = fmaf(p4.w, v4.w, oa);
    }
    qo[row * 512 + h * 64 + lane] = f2bf(oa / s);
    __syncthreads();
  }
}

// ---------------------------------------------------------------------------
// Inputs FP32; OUTPUT FP32 (reference returns float32 — round-3 bf16 output
// write decoded as fp32 pairs explains the 1.203 absmax; fixed here).
// Workspace layout (bytes), total 55,574,528:
//   qbuf  @ 0        : 50176*512*2 = 51,380,224  bf16 (q, then attn out)
//   kvbuf @ 51380224 : 1024*1024*4 =  4,194,304  fp32
// ---------------------------------------------------------------------------
extern "C" void kernel_launch(void* const* d_in, const int* in_sizes, int n_in,
                              void* d_out, int out_size, void* d_ws,
                              size_t ws_size, hipStream_t stream) {
  const float* x = (const float*)d_in[0];
  const float* Wq = (const float*)d_in[1];
  const float* Wkv = (const float*)d_in[2];
  const float* Wo = (const float*)d_in[3];
  const float* bo = (const float*)d_in[4];
  float* out = (float*)d_out;

  char* ws = (char*)d_ws;
  ushort_t* qbuf = (ushort_t*)(ws);
  float* kvbuf = (float*)(ws + 51380224);

  // 1) Q projection: [50176,256] x [256,512] -> bf16 qbuf
  hipLaunchKernelGGL((gemm_any<float, ushort_t>), dim3(512 / BN, 50176 / BM),
                     dim3(256), 0, stream, x, Wq, (const float*)nullptr, qbuf,
                     50176, 512, 256, 0);
  // 2) KV conv as GEMM (fused im2col): [1024,12544] x [12544,1024] -> fp32
  hipLaunchKernelGGL(gemm_kv, dim3(1024 / BN, 1024 / BM), dim3(256), 0, stream,
                     x, Wkv, kvbuf);
  // 3) attention, in-place on qbuf
  hipLaunchKernelGGL(attn_kernel, dim3(49, 128), dim3(256), 0, stream, qbuf,
                     kvbuf);
  // 4) output projection + bias: [50176,512] x [512,256] -> fp32 out
  hipLaunchKernelGGL((gemm_any<ushort_t, float>), dim3(256 / BN, 50176 / BM),
                     dim3(256), 0, stream, qbuf, Wo, bo, out, 50176, 256, 512,
                     1);
}

// Round 5
// 617.830 us; speedup vs baseline: 2.2224x; 2.2224x over previous
//
#include <hip/hip_runtime.h>
#include <stdint.h>

typedef unsigned short ushort_t;
typedef __attribute__((ext_vector_type(8))) unsigned short ushort8v;
typedef __attribute__((ext_vector_type(8))) short short8v;  // 8 bf16 = 4 VGPRs
typedef __attribute__((ext_vector_type(4))) float f32x4;    // MFMA C/D frag

__device__ __forceinline__ float bf2f(ushort_t u) {
  union { unsigned int i; float f; } v;
  v.i = ((unsigned int)u) << 16;
  return v.f;
}
__device__ __forceinline__ ushort_t f2bf(float f) {
  union { float f; unsigned int i; } v;
  v.f = f;
  unsigned int r = v.i + 0x7FFFu + ((v.i >> 16) & 1u);  // RNE
  return (ushort_t)(r >> 16);
}

// Load 8 elements as bf16 bit-pattern vector (cvt if source is fp32).
__device__ __forceinline__ ushort8v load8bf(const ushort_t* __restrict__ p) {
  return *(const ushort8v*)p;
}
__device__ __forceinline__ ushort8v load8bf(const float* __restrict__ p) {
  const float4 a = *(const float4*)p;
  const float4 b = *(const float4*)(p + 4);
  ushort8v r;
  r[0] = f2bf(a.x); r[1] = f2bf(a.y); r[2] = f2bf(a.z); r[3] = f2bf(a.w);
  r[4] = f2bf(b.x); r[5] = f2bf(b.y); r[6] = f2bf(b.z); r[7] = f2bf(b.w);
  return r;
}
__device__ __forceinline__ void storeC(float* p, float v) { *p = v; }
__device__ __forceinline__ void storeC(ushort_t* p, float v) { *p = f2bf(v); }

// ---------------------------------------------------------------------------
// Transpose + fp32->bf16: W[K][N] -> WT[N][K].  32x32 tiles, 256 threads.
// ---------------------------------------------------------------------------
__global__ __launch_bounds__(256) void transpose_cvt(
    const float* __restrict__ W, ushort_t* __restrict__ WT, int K, int N) {
  __shared__ float tile[32][33];
  const int t = threadIdx.x;
  const int k0 = blockIdx.y * 32;
  const int n0 = blockIdx.x * 32;
  {
    const int r = t >> 3, c4 = (t & 7) * 4;
    const float4 v = *(const float4*)(W + (size_t)(k0 + r) * N + n0 + c4);
    tile[r][c4] = v.x; tile[r][c4 + 1] = v.y;
    tile[r][c4 + 2] = v.z; tile[r][c4 + 3] = v.w;
  }
  __syncthreads();
  {
    const int rn = t >> 3, ck = (t & 7) * 4;
    union { ushort_t u[4]; uint2 v; } o;
#pragma unroll
    for (int j = 0; j < 4; ++j) o.u[j] = f2bf(tile[ck + j][rn]);
    *(uint2*)(WT + (size_t)(n0 + rn) * K + k0 + ck) = o.v;
  }
}

// ---------------------------------------------------------------------------
// MFMA NT GEMM: C[M][N] = A[M][K] * BT[N][K]^T (+bias).
// 128x128 block, BK=32, 256 thr (4 waves 2x2), 4x4 16x16x32 MFMAs per wave.
// LDS is fragment-major ([tile16][lane][8 bf16]) -> frag reads are
// lane-contiguous ds_read_b128, conflict-free.
// ---------------------------------------------------------------------------
template <typename TA, typename TC>
__global__ __launch_bounds__(256) void gemm_mfma_nt(
    const TA* __restrict__ A, const ushort_t* __restrict__ BT,
    const float* __restrict__ bias, TC* __restrict__ C,
    int M, int N, int K, int has_bias) {
  __shared__ ushort_t lA[8 * 512];
  __shared__ ushort_t lB[8 * 512];
  const int t = threadIdx.x;
  const int m0 = blockIdx.y * 128;
  const int n0 = blockIdx.x * 128;
  const int lane = t & 63;
  const int wm = (t >> 6) >> 1, wn = (t >> 6) & 1;

  f32x4 acc[4][4] = {};

  const int sm = t >> 2;   // 0..63
  const int kq = t & 3;    // 16B chunk within 32-wide K tile

  for (int k0 = 0; k0 < K; k0 += 32) {
#pragma unroll
    for (int h = 0; h < 2; ++h) {
      const int m = h * 64 + sm;  // 0..127
      const int off = (m >> 4) * 512 + (kq * 16 + (m & 15)) * 8;
      const ushort8v av = load8bf(A + (size_t)(m0 + m) * K + k0 + kq * 8);
      *(ushort8v*)&lA[off] = av;
      const ushort8v bv = load8bf(BT + (size_t)(n0 + m) * K + k0 + kq * 8);
      *(ushort8v*)&lB[off] = bv;
    }
    __syncthreads();
    short8v af[4], bf[4];
#pragma unroll
    for (int i = 0; i < 4; ++i) {
      af[i] = *(const short8v*)&lA[(wm * 4 + i) * 512 + lane * 8];
      bf[i] = *(const short8v*)&lB[(wn * 4 + i) * 512 + lane * 8];
    }
#pragma unroll
    for (int i = 0; i < 4; ++i)
#pragma unroll
      for (int j = 0; j < 4; ++j)
        acc[i][j] = __builtin_amdgcn_mfma_f32_16x16x32_bf16(
            af[i], bf[j], acc[i][j], 0, 0, 0);
    __syncthreads();
  }

  const int col = lane & 15, rq = (lane >> 4) * 4;
#pragma unroll
  for (int i = 0; i < 4; ++i) {
    const int mb = m0 + (wm * 4 + i) * 16 + rq;
#pragma unroll
    for (int j = 0; j < 4; ++j) {
      const int nb = n0 + (wn * 4 + j) * 16 + col;
      const float badd = has_bias ? bias[nb] : 0.f;
#pragma unroll
      for (int r = 0; r < 4; ++r)
        storeC(&C[(size_t)(mb + r) * N + nb], acc[i][j][r] + badd);
    }
  }
}

// ---------------------------------------------------------------------------
// KV conv GEMM, MFMA, fused im2col gather, split-K (S=14, chunk 896).
// C[1024][1024] += A_im2col[1024][k-chunk] * WkvT[1024][k-chunk]^T via
// fp32 atomicAdd (kvbuf zeroed beforehand).
// ---------------------------------------------------------------------------
__global__ __launch_bounds__(256) void gemm_kv_mfma(
    const float* __restrict__ x, const ushort_t* __restrict__ WkvT,
    float* __restrict__ C) {
  __shared__ ushort_t lA[8 * 512];
  __shared__ ushort_t lB[8 * 512];
  const int t = threadIdx.x;
  const int m0 = blockIdx.y * 128;
  const int n0 = blockIdx.x * 128;
  const int kbeg = blockIdx.z * 896;
  const int lane = t & 63;
  const int wm = (t >> 6) >> 1, wn = (t >> 6) & 1;

  f32x4 acc[4][4] = {};

  const int sm = t >> 2;
  const int kq = t & 3;

  for (int k0 = kbeg; k0 < kbeg + 896; k0 += 32) {
#pragma unroll
    for (int h = 0; h < 2; ++h) {
      const int m = h * 64 + sm;
      const int off = (m >> 4) * 512 + (kq * 16 + (m & 15)) * 8;
      // im2col gather: pooled pos (m0+m) -> pixel, k -> (patch, channel)
      const int gm = m0 + m;
      const int b = gm >> 6, ty = (gm >> 3) & 7, tx = gm & 7;
      const int k = k0 + kq * 8;
      const int patch = k >> 8;          // 0..48
      const int c = k & 255;             // 8-aligned
      const int dy = (patch * 37) >> 8;  // exact /7 for patch<49
      const int dx = patch - dy * 7;
      const int pix = b * 3136 + (ty * 7 + dy) * 56 + (tx * 7 + dx);
      const ushort8v av = load8bf(x + (size_t)pix * 256 + c);
      *(ushort8v*)&lA[off] = av;
      const ushort8v bv =
          load8bf(WkvT + (size_t)(n0 + m) * 12544 + k0 + kq * 8);
      *(ushort8v*)&lB[off] = bv;
    }
    __syncthreads();
    short8v af[4], bf[4];
#pragma unroll
    for (int i = 0; i < 4; ++i) {
      af[i] = *(const short8v*)&lA[(wm * 4 + i) * 512 + lane * 8];
      bf[i] = *(const short8v*)&lB[(wn * 4 + i) * 512 + lane * 8];
    }
#pragma unroll
    for (int i = 0; i < 4; ++i)
#pragma unroll
      for (int j = 0; j < 4; ++j)
        acc[i][j] = __builtin_amdgcn_mfma_f32_16x16x32_bf16(
            af[i], bf[j], acc[i][j], 0, 0, 0);
    __syncthreads();
  }

  const int col = lane & 15, rq = (lane >> 4) * 4;
#pragma unroll
  for (int i = 0; i < 4; ++i) {
    const int mb = m0 + (wm * 4 + i) * 16 + rq;
#pragma unroll
    for (int j = 0; j < 4; ++j) {
      const int nb = n0 + (wn * 4 + j) * 16 + col;
#pragma unroll
      for (int r = 0; r < 4; ++r)
        atomicAdd(&C[(size_t)(mb + r) * 1024 + nb], acc[i][j][r]);
    }
  }
}

// ---------------------------------------------------------------------------
// Attention, IN-PLACE on bf16 q buffer (unchanged from round 4).
// ---------------------------------------------------------------------------
__global__ __launch_bounds__(256) void attn_kernel(
    ushort_t* __restrict__ qo, const float* __restrict__ kv) {
  __shared__ float Ks[64][68];
  __shared__ float VsT[64][68];
  __shared__ float qs[4][64];
  __shared__ float ps[4][64];
  const int t = threadIdx.x;
  const int bh = blockIdx.y;
  const int b = bh >> 3, h = bh & 7;
  const int chunk = blockIdx.x;
  const float* kvp = kv + (size_t)(b * 64) * 1024 + h * 64;

  for (int i = t; i < 4096; i += 256) {
    const int pos = i >> 6, d = i & 63;
    Ks[pos][d] = kvp[pos * 1024 + d];
    const int pos2 = i & 63, d2 = i >> 6;
    VsT[d2][pos2] = kvp[pos2 * 1024 + 512 + d2];
  }
  __syncthreads();

  const int w = t >> 6, lane = t & 63;
  for (int it = 0; it < 16; ++it) {
    const int p = chunk * 64 + it * 4 + w;
    const size_t row = (size_t)b * 3136 + p;
    const float qv = bf2f(qo[row * 512 + h * 64 + lane]);
    qs[w][lane] = qv;
    __syncthreads();

    float acc = 0.f;
#pragma unroll
    for (int d4 = 0; d4 < 64; d4 += 4) {
      const float4 q4 = *(const float4*)&qs[w][d4];
      const float4 k4 = *(const float4*)&Ks[lane][d4];
      acc = fmaf(q4.x, k4.x, acc);
      acc = fmaf(q4.y, k4.y, acc);
      acc = fmaf(q4.z, k4.z, acc);
      acc = fmaf(q4.w, k4.w, acc);
    }
    acc *= 0.125f;

    float mx = acc;
#pragma unroll
    for (int off = 32; off >= 1; off >>= 1) mx = fmaxf(mx, __shfl_xor(mx, off));
    const float pe = __expf(acc - mx);
    float s = pe;
#pragma unroll
    for (int off = 32; off >= 1; off >>= 1) s += __shfl_xor(s, off);
    ps[w][lane] = pe;
    __syncthreads();

    float oa = 0.f;
#pragma unroll
    for (int l4 = 0; l4 < 64; l4 += 4) {
      const float4 p4 = *(const float4*)&ps[w][l4];
      const float4 v4 = *(const float4*)&VsT[lane][l4];
      oa = fmaf(p4.x, v4.x, oa);
      oa = fmaf(p4.y, v4.y, oa);
      oa = fmaf(p4.z, v4.z, oa);
      oa = fmaf(p4.w, v4.w, oa);
    }
    qo[row * 512 + h * 64 + lane] = f2bf(oa / s);
    __syncthreads();
  }
}

// ---------------------------------------------------------------------------
// Workspace (bytes), total 81,788,928:
//   qbuf  @ 0        : 50176*512*2  = 51,380,224  bf16 (q, then attn out)
//   kvbuf @ 51380224 : 1024*1024*4  =  4,194,304  fp32 (atomic split-K)
//   WkvT  @ 55574528 : 1024*12544*2 = 25,690,112  bf16
//   WqT   @ 81264640 : 512*256*2    =     262,144 bf16
//   WoT   @ 81526784 : 256*512*2    =     262,144 bf16
// ---------------------------------------------------------------------------
extern "C" void kernel_launch(void* const* d_in, const int* in_sizes, int n_in,
                              void* d_out, int out_size, void* d_ws,
                              size_t ws_size, hipStream_t stream) {
  const float* x = (const float*)d_in[0];
  const float* Wq = (const float*)d_in[1];
  const float* Wkv = (const float*)d_in[2];
  const float* Wo = (const float*)d_in[3];
  const float* bo = (const float*)d_in[4];
  float* out = (float*)d_out;

  char* ws = (char*)d_ws;
  ushort_t* qbuf = (ushort_t*)(ws);
  float* kvbuf = (float*)(ws + 51380224);
  ushort_t* WkvT = (ushort_t*)(ws + 55574528);
  ushort_t* WqT = (ushort_t*)(ws + 81264640);
  ushort_t* WoT = (ushort_t*)(ws + 81526784);

  // 0) weight transposes + bf16 cvt; kvbuf zero for atomic split-K
  hipLaunchKernelGGL(transpose_cvt, dim3(16, 8), dim3(256), 0, stream, Wq, WqT,
                     256, 512);
  hipLaunchKernelGGL(transpose_cvt, dim3(32, 392), dim3(256), 0, stream, Wkv,
                     WkvT, 12544, 1024);
  hipLaunchKernelGGL(transpose_cvt, dim3(8, 16), dim3(256), 0, stream, Wo, WoT,
                     512, 256);
  hipMemsetAsync(kvbuf, 0, 1024 * 1024 * 4, stream);

  // 1) Q projection: [50176,256] x [256,512] -> bf16 qbuf
  hipLaunchKernelGGL((gemm_mfma_nt<float, ushort_t>), dim3(4, 392), dim3(256),
                     0, stream, x, WqT, (const float*)nullptr, qbuf, 50176, 512,
                     256, 0);
  // 2) KV conv GEMM, split-K=14: [1024,12544] x [12544,1024] -> fp32 atomic
  hipLaunchKernelGGL(gemm_kv_mfma, dim3(8, 8, 14), dim3(256), 0, stream, x,
                     WkvT, kvbuf);
  // 3) attention, in-place on qbuf
  hipLaunchKernelGGL(attn_kernel, dim3(49, 128), dim3(256), 0, stream, qbuf,
                     kvbuf);
  // 4) output projection + bias: [50176,512] x [512,256] -> fp32 out
  hipLaunchKernelGGL((gemm_mfma_nt<ushort_t, float>), dim3(2, 392), dim3(256),
                     0, stream, qbuf, WoT, bo, out, 50176, 256, 512, 1);
}

// Round 6
// 390.382 us; speedup vs baseline: 3.5172x; 1.5826x over previous
//
#include <hip/hip_runtime.h>
#include <stdint.h>

typedef unsigned short ushort_t;
typedef __attribute__((ext_vector_type(8))) unsigned short ushort8v;
typedef __attribute__((ext_vector_type(8))) short short8v;  // 8 bf16 = 4 VGPRs
typedef __attribute__((ext_vector_type(4))) float f32x4;    // MFMA C/D frag

__device__ __forceinline__ float bf2f(ushort_t u) {
  union { unsigned int i; float f; } v;
  v.i = ((unsigned int)u) << 16;
  return v.f;
}
__device__ __forceinline__ ushort_t f2bf(float f) {
  union { float f; unsigned int i; } v;
  v.f = f;
  unsigned int r = v.i + 0x7FFFu + ((v.i >> 16) & 1u);  // RNE
  return (ushort_t)(r >> 16);
}

// Load 8 elements as bf16 bit-pattern vector (cvt if source is fp32).
__device__ __forceinline__ ushort8v load8bf(const ushort_t* __restrict__ p) {
  return *(const ushort8v*)p;
}
__device__ __forceinline__ ushort8v load8bf(const float* __restrict__ p) {
  const float4 a = *(const float4*)p;
  const float4 b = *(const float4*)(p + 4);
  ushort8v r;
  r[0] = f2bf(a.x); r[1] = f2bf(a.y); r[2] = f2bf(a.z); r[3] = f2bf(a.w);
  r[4] = f2bf(b.x); r[5] = f2bf(b.y); r[6] = f2bf(b.z); r[7] = f2bf(b.w);
  return r;
}
__device__ __forceinline__ void storeC(float* p, float v) { *p = v; }
__device__ __forceinline__ void storeC(ushort_t* p, float v) { *p = f2bf(v); }

// ---------------------------------------------------------------------------
// Transpose + fp32->bf16: W[K][N] -> WT[N][K].  32x32 tiles, 256 threads.
// ---------------------------------------------------------------------------
__global__ __launch_bounds__(256) void transpose_cvt(
    const float* __restrict__ W, ushort_t* __restrict__ WT, int K, int N) {
  __shared__ float tile[32][33];
  const int t = threadIdx.x;
  const int k0 = blockIdx.y * 32;
  const int n0 = blockIdx.x * 32;
  {
    const int r = t >> 3, c4 = (t & 7) * 4;
    const float4 v = *(const float4*)(W + (size_t)(k0 + r) * N + n0 + c4);
    tile[r][c4] = v.x; tile[r][c4 + 1] = v.y;
    tile[r][c4 + 2] = v.z; tile[r][c4 + 3] = v.w;
  }
  __syncthreads();
  {
    const int rn = t >> 3, ck = (t & 7) * 4;
    union { ushort_t u[4]; uint2 v; } o;
#pragma unroll
    for (int j = 0; j < 4; ++j) o.u[j] = f2bf(tile[ck + j][rn]);
    *(uint2*)(WT + (size_t)(n0 + rn) * K + k0 + ck) = o.v;
  }
}

// ---------------------------------------------------------------------------
// fp32 -> bf16 bulk convert (n % 1024 == 0), 4 elems/thread.
// ---------------------------------------------------------------------------
__global__ __launch_bounds__(256) void cvt_f32_bf16(
    const float* __restrict__ in, ushort_t* __restrict__ out) {
  const int i = (blockIdx.x * 256 + threadIdx.x) * 4;
  const float4 v = *(const float4*)(in + i);
  union { ushort_t u[4]; uint2 q; } o;
  o.u[0] = f2bf(v.x); o.u[1] = f2bf(v.y);
  o.u[2] = f2bf(v.z); o.u[3] = f2bf(v.w);
  *(uint2*)(out + i) = o.q;
}

// ---------------------------------------------------------------------------
// MFMA NT GEMM: C[M][N] = A[M][K] * BT[N][K]^T (+bias).  (round-5 proven)
// ---------------------------------------------------------------------------
template <typename TA, typename TC>
__global__ __launch_bounds__(256) void gemm_mfma_nt(
    const TA* __restrict__ A, const ushort_t* __restrict__ BT,
    const float* __restrict__ bias, TC* __restrict__ C,
    int M, int N, int K, int has_bias) {
  __shared__ ushort_t lA[8 * 512];
  __shared__ ushort_t lB[8 * 512];
  const int t = threadIdx.x;
  const int m0 = blockIdx.y * 128;
  const int n0 = blockIdx.x * 128;
  const int lane = t & 63;
  const int wm = (t >> 6) >> 1, wn = (t >> 6) & 1;

  f32x4 acc[4][4] = {};

  const int sm = t >> 2;   // 0..63
  const int kq = t & 3;    // 16B chunk within 32-wide K tile

  for (int k0 = 0; k0 < K; k0 += 32) {
#pragma unroll
    for (int h = 0; h < 2; ++h) {
      const int m = h * 64 + sm;  // 0..127
      const int off = (m >> 4) * 512 + (kq * 16 + (m & 15)) * 8;
      const ushort8v av = load8bf(A + (size_t)(m0 + m) * K + k0 + kq * 8);
      *(ushort8v*)&lA[off] = av;
      const ushort8v bv = load8bf(BT + (size_t)(n0 + m) * K + k0 + kq * 8);
      *(ushort8v*)&lB[off] = bv;
    }
    __syncthreads();
    short8v af[4], bf[4];
#pragma unroll
    for (int i = 0; i < 4; ++i) {
      af[i] = *(const short8v*)&lA[(wm * 4 + i) * 512 + lane * 8];
      bf[i] = *(const short8v*)&lB[(wn * 4 + i) * 512 + lane * 8];
    }
#pragma unroll
    for (int i = 0; i < 4; ++i)
#pragma unroll
      for (int j = 0; j < 4; ++j)
        acc[i][j] = __builtin_amdgcn_mfma_f32_16x16x32_bf16(
            af[i], bf[j], acc[i][j], 0, 0, 0);
    __syncthreads();
  }

  const int col = lane & 15, rq = (lane >> 4) * 4;
#pragma unroll
  for (int i = 0; i < 4; ++i) {
    const int mb = m0 + (wm * 4 + i) * 16 + rq;
#pragma unroll
    for (int j = 0; j < 4; ++j) {
      const int nb = n0 + (wn * 4 + j) * 16 + col;
      const float badd = has_bias ? bias[nb] : 0.f;
#pragma unroll
      for (int r = 0; r < 4; ++r)
        storeC(&C[(size_t)(mb + r) * N + nb], acc[i][j][r] + badd);
    }
  }
}

// ---------------------------------------------------------------------------
// KV conv GEMM, MFMA, fused im2col gather, split-K (S=14).  (round-5 proven)
// ---------------------------------------------------------------------------
__global__ __launch_bounds__(256) void gemm_kv_mfma(
    const float* __restrict__ x, const ushort_t* __restrict__ WkvT,
    float* __restrict__ C) {
  __shared__ ushort_t lA[8 * 512];
  __shared__ ushort_t lB[8 * 512];
  const int t = threadIdx.x;
  const int m0 = blockIdx.y * 128;
  const int n0 = blockIdx.x * 128;
  const int kbeg = blockIdx.z * 896;
  const int lane = t & 63;
  const int wm = (t >> 6) >> 1, wn = (t >> 6) & 1;

  f32x4 acc[4][4] = {};

  const int sm = t >> 2;
  const int kq = t & 3;

  for (int k0 = kbeg; k0 < kbeg + 896; k0 += 32) {
#pragma unroll
    for (int h = 0; h < 2; ++h) {
      const int m = h * 64 + sm;
      const int off = (m >> 4) * 512 + (kq * 16 + (m & 15)) * 8;
      const int gm = m0 + m;
      const int b = gm >> 6, ty = (gm >> 3) & 7, tx = gm & 7;
      const int k = k0 + kq * 8;
      const int patch = k >> 8;          // 0..48
      const int c = k & 255;             // 8-aligned
      const int dy = (patch * 37) >> 8;  // exact /7 for patch<49
      const int dx = patch - dy * 7;
      const int pix = b * 3136 + (ty * 7 + dy) * 56 + (tx * 7 + dx);
      const ushort8v av = load8bf(x + (size_t)pix * 256 + c);
      *(ushort8v*)&lA[off] = av;
      const ushort8v bv =
          load8bf(WkvT + (size_t)(n0 + m) * 12544 + k0 + kq * 8);
      *(ushort8v*)&lB[off] = bv;
    }
    __syncthreads();
    short8v af[4], bf[4];
#pragma unroll
    for (int i = 0; i < 4; ++i) {
      af[i] = *(const short8v*)&lA[(wm * 4 + i) * 512 + lane * 8];
      bf[i] = *(const short8v*)&lB[(wn * 4 + i) * 512 + lane * 8];
    }
#pragma unroll
    for (int i = 0; i < 4; ++i)
#pragma unroll
      for (int j = 0; j < 4; ++j)
        acc[i][j] = __builtin_amdgcn_mfma_f32_16x16x32_bf16(
            af[i], bf[j], acc[i][j], 0, 0, 0);
    __syncthreads();
  }

  const int col = lane & 15, rq = (lane >> 4) * 4;
#pragma unroll
  for (int i = 0; i < 4; ++i) {
    const int mb = m0 + (wm * 4 + i) * 16 + rq;
#pragma unroll
    for (int j = 0; j < 4; ++j) {
      const int nb = n0 + (wn * 4 + j) * 16 + col;
#pragma unroll
      for (int r = 0; r < 4; ++r)
        atomicAdd(&C[(size_t)(mb + r) * 1024 + nb], acc[i][j][r]);
    }
  }
}

// ---------------------------------------------------------------------------
// MFMA attention, in-place on bf16 qbuf.  kvb: [1024][1024] bf16.
// Block = 256 thr = 4 waves; wave handles 64 queries of one (b,h).
// S = QK^T (Q,K frags straight from global, 32 MFMAs) -> reg softmax
// (in-lane over j-tiles + shfl_xor over 16-lane col group) -> P via per-wave
// LDS (C-layout -> A-layout, m120 pattern) -> PV (32 MFMAs) -> /l -> store.
// Fragment maps (verified via passing GEMM): A/B lane: m|n=lane&15,
// k=(lane>>4)*8+j ; C/D lane: col=lane&15, row=(lane>>4)*4+reg.
// ---------------------------------------------------------------------------
__global__ __launch_bounds__(256) void attn_mfma(
    ushort_t* __restrict__ qo, const ushort_t* __restrict__ kvb) {
  __shared__ ushort_t VT[64][72];      // [d][key], 72-short rows (16B-aligned)
  __shared__ ushort_t P[4][64][72];    // per-wave [query][key]
  const int t = threadIdx.x;
  const int lane = t & 63;
  const int w = t >> 6;
  const int bh = blockIdx.y;
  const int b = bh >> 3, h = bh & 7;
  const ushort_t* kvp = kvb + (size_t)(b * 64) * 1024 + h * 64;

  // Stage V^T: thread reads 8 d of one key, scatters to VT columns.
  for (int i = t; i < 512; i += 256) {
    const int key = i >> 3, d0 = (i & 7) * 8;
    const ushort8v v = *(const ushort8v*)(kvp + (size_t)key * 1024 + 512 + d0);
#pragma unroll
    for (int jj = 0; jj < 8; ++jj) VT[d0 + jj][key] = v[jj];
  }
  __syncthreads();

  const int q0_raw = blockIdx.x * 256 + w * 64;
  const bool valid = q0_raw < 3136;
  const int q0 = valid ? q0_raw : 3072;  // clamped redundant compute, no store
  const size_t qbase = ((size_t)b * 3136 + q0) * 512 + h * 64;

  const int lm = lane & 15, quad = lane >> 4;

  // Q a-frags and K b-frags directly from global (b128 each).
  short8v qf[4][2], kf[4][2];
#pragma unroll
  for (int i = 0; i < 4; ++i)
#pragma unroll
    for (int s = 0; s < 2; ++s) {
      qf[i][s] = *(const short8v*)(qo + qbase + (size_t)(16 * i + lm) * 512 +
                                   32 * s + quad * 8);
      kf[i][s] = *(const short8v*)(kvp + (size_t)(16 * i + lm) * 1024 +
                                   32 * s + quad * 8);
    }

  // S = Q K^T  [i: query tile, j: key tile]
  f32x4 sa[4][4];
#pragma unroll
  for (int i = 0; i < 4; ++i)
#pragma unroll
    for (int j = 0; j < 4; ++j) {
      f32x4 z = {};
      z = __builtin_amdgcn_mfma_f32_16x16x32_bf16(qf[i][0], kf[j][0], z, 0, 0, 0);
      sa[i][j] = __builtin_amdgcn_mfma_f32_16x16x32_bf16(qf[i][1], kf[j][1], z, 0, 0, 0);
    }

  // Softmax over 64 keys: in-lane over j, shfl over the 16 col-lanes.
  float l[4][4];
#pragma unroll
  for (int i = 0; i < 4; ++i)
#pragma unroll
    for (int r = 0; r < 4; ++r) {
      float m = fmaxf(fmaxf(sa[i][0][r], sa[i][1][r]),
                      fmaxf(sa[i][2][r], sa[i][3][r]));
#pragma unroll
      for (int off = 1; off < 16; off <<= 1) m = fmaxf(m, __shfl_xor(m, off));
      float sum = 0.f;
#pragma unroll
      for (int j = 0; j < 4; ++j) {
        const float p = __expf(0.125f * (sa[i][j][r] - m));
        sa[i][j][r] = p;
        sum += p;
      }
#pragma unroll
      for (int off = 1; off < 16; off <<= 1) sum += __shfl_xor(sum, off);
      l[i][r] = sum;
    }

  // P: C-layout regs -> per-wave LDS tile (bf16).
#pragma unroll
  for (int i = 0; i < 4; ++i) {
    const int row = 16 * i + quad * 4;
#pragma unroll
    for (int j = 0; j < 4; ++j) {
      const int col = 16 * j + lm;
#pragma unroll
      for (int r = 0; r < 4; ++r) P[w][row + r][col] = f2bf(sa[i][j][r]);
    }
  }
  __syncthreads();  // visibility of P (and converged waves)

  // V b-frags from VT; PV.
  short8v vf[4][2];
#pragma unroll
  for (int jn = 0; jn < 4; ++jn)
#pragma unroll
    for (int s2 = 0; s2 < 2; ++s2)
      vf[jn][s2] = *(const short8v*)&VT[16 * jn + lm][32 * s2 + quad * 8];

  f32x4 oa[4][4];
#pragma unroll
  for (int i = 0; i < 4; ++i) {
    const short8v pf0 = *(const short8v*)&P[w][16 * i + lm][quad * 8];
    const short8v pf1 = *(const short8v*)&P[w][16 * i + lm][32 + quad * 8];
#pragma unroll
    for (int jn = 0; jn < 4; ++jn) {
      f32x4 z = {};
      z = __builtin_amdgcn_mfma_f32_16x16x32_bf16(pf0, vf[jn][0], z, 0, 0, 0);
      oa[i][jn] = __builtin_amdgcn_mfma_f32_16x16x32_bf16(pf1, vf[jn][1], z, 0, 0, 0);
    }
  }

  // Epilogue: divide by l, store in-place (block owns its rows exclusively).
  if (valid) {
#pragma unroll
    for (int i = 0; i < 4; ++i) {
#pragma unroll
      for (int r = 0; r < 4; ++r) {
        const float inv = 1.f / l[i][r];
        const size_t rowoff = qbase + (size_t)(16 * i + quad * 4 + r) * 512;
#pragma unroll
        for (int jn = 0; jn < 4; ++jn)
          qo[rowoff + 16 * jn + lm] = f2bf(oa[i][jn][r] * inv);
      }
    }
  }
}

// ---------------------------------------------------------------------------
// Workspace (bytes), total 83,886,080:
//   qbuf  @ 0        : 50176*512*2  = 51,380,224  bf16 (q, then attn out)
//   kvbuf @ 51380224 : 1024*1024*4  =  4,194,304  fp32 (atomic split-K)
//   WkvT  @ 55574528 : 1024*12544*2 = 25,690,112  bf16
//   WqT   @ 81264640 : 512*256*2    =     262,144 bf16
//   WoT   @ 81526784 : 256*512*2    =     262,144 bf16
//   kvbf  @ 81788928 : 1024*1024*2  =  2,097,152  bf16
// ---------------------------------------------------------------------------
extern "C" void kernel_launch(void* const* d_in, const int* in_sizes, int n_in,
                              void* d_out, int out_size, void* d_ws,
                              size_t ws_size, hipStream_t stream) {
  const float* x = (const float*)d_in[0];
  const float* Wq = (const float*)d_in[1];
  const float* Wkv = (const float*)d_in[2];
  const float* Wo = (const float*)d_in[3];
  const float* bo = (const float*)d_in[4];
  float* out = (float*)d_out;

  char* ws = (char*)d_ws;
  ushort_t* qbuf = (ushort_t*)(ws);
  float* kvbuf = (float*)(ws + 51380224);
  ushort_t* WkvT = (ushort_t*)(ws + 55574528);
  ushort_t* WqT = (ushort_t*)(ws + 81264640);
  ushort_t* WoT = (ushort_t*)(ws + 81526784);
  ushort_t* kvbf = (ushort_t*)(ws + 81788928);

  // 0) weight transposes + bf16 cvt; kvbuf zero for atomic split-K
  hipLaunchKernelGGL(transpose_cvt, dim3(16, 8), dim3(256), 0, stream, Wq, WqT,
                     256, 512);
  hipLaunchKernelGGL(transpose_cvt, dim3(32, 392), dim3(256), 0, stream, Wkv,
                     WkvT, 12544, 1024);
  hipLaunchKernelGGL(transpose_cvt, dim3(8, 16), dim3(256), 0, stream, Wo, WoT,
                     512, 256);
  hipMemsetAsync(kvbuf, 0, 1024 * 1024 * 4, stream);

  // 1) Q projection: [50176,256] x [256,512] -> bf16 qbuf
  hipLaunchKernelGGL((gemm_mfma_nt<float, ushort_t>), dim3(4, 392), dim3(256),
                     0, stream, x, WqT, (const float*)nullptr, qbuf, 50176, 512,
                     256, 0);
  // 2) KV conv GEMM, split-K=14 -> fp32 atomic; then cvt to bf16
  hipLaunchKernelGGL(gemm_kv_mfma, dim3(8, 8, 14), dim3(256), 0, stream, x,
                     WkvT, kvbuf);
  hipLaunchKernelGGL(cvt_f32_bf16, dim3(1024), dim3(256), 0, stream, kvbuf,
                     kvbf);
  // 3) MFMA attention, in-place on qbuf
  hipLaunchKernelGGL(attn_mfma, dim3(13, 128), dim3(256), 0, stream, qbuf,
                     kvbf);
  // 4) output projection + bias: [50176,512] x [512,256] -> fp32 out
  hipLaunchKernelGGL((gemm_mfma_nt<ushort_t, float>), dim3(2, 392), dim3(256),
                     0, stream, qbuf, WoT, bo, out, 50176, 256, 512, 1);
}

// Round 7
// 366.140 us; speedup vs baseline: 3.7500x; 1.0662x over previous
//
#include <hip/hip_runtime.h>
#include <stdint.h>

typedef unsigned short ushort_t;
typedef __attribute__((ext_vector_type(8))) unsigned short ushort8v;
typedef __attribute__((ext_vector_type(8))) short short8v;  // 8 bf16 = 4 VGPRs
typedef __attribute__((ext_vector_type(4))) float f32x4;    // MFMA C/D frag

__device__ __forceinline__ float bf2f(ushort_t u) {
  union { unsigned int i; float f; } v;
  v.i = ((unsigned int)u) << 16;
  return v.f;
}
__device__ __forceinline__ ushort_t f2bf(float f) {
  union { float f; unsigned int i; } v;
  v.f = f;
  unsigned int r = v.i + 0x7FFFu + ((v.i >> 16) & 1u);  // RNE
  return (ushort_t)(r >> 16);
}

// Load 8 elements as bf16 bit-pattern vector (cvt if source is fp32).
__device__ __forceinline__ ushort8v load8bf(const ushort_t* __restrict__ p) {
  return *(const ushort8v*)p;
}
__device__ __forceinline__ ushort8v load8bf(const float* __restrict__ p) {
  const float4 a = *(const float4*)p;
  const float4 b = *(const float4*)(p + 4);
  ushort8v r;
  r[0] = f2bf(a.x); r[1] = f2bf(a.y); r[2] = f2bf(a.z); r[3] = f2bf(a.w);
  r[4] = f2bf(b.x); r[5] = f2bf(b.y); r[6] = f2bf(b.z); r[7] = f2bf(b.w);
  return r;
}
__device__ __forceinline__ void storeC(float* p, float v) { *p = v; }
__device__ __forceinline__ void storeC(ushort_t* p, float v) { *p = f2bf(v); }

// ---------------------------------------------------------------------------
// Transpose + fp32->bf16: W[K][N] -> WT[N][K].  32x32 tiles, 256 threads.
// ---------------------------------------------------------------------------
__global__ __launch_bounds__(256) void transpose_cvt(
    const float* __restrict__ W, ushort_t* __restrict__ WT, int K, int N) {
  __shared__ float tile[32][33];
  const int t = threadIdx.x;
  const int k0 = blockIdx.y * 32;
  const int n0 = blockIdx.x * 32;
  {
    const int r = t >> 3, c4 = (t & 7) * 4;
    const float4 v = *(const float4*)(W + (size_t)(k0 + r) * N + n0 + c4);
    tile[r][c4] = v.x; tile[r][c4 + 1] = v.y;
    tile[r][c4 + 2] = v.z; tile[r][c4 + 3] = v.w;
  }
  __syncthreads();
  {
    const int rn = t >> 3, ck = (t & 7) * 4;
    union { ushort_t u[4]; uint2 v; } o;
#pragma unroll
    for (int j = 0; j < 4; ++j) o.u[j] = f2bf(tile[ck + j][rn]);
    *(uint2*)(WT + (size_t)(n0 + rn) * K + k0 + ck) = o.v;
  }
}

// ---------------------------------------------------------------------------
// fp32 -> bf16 bulk convert (n % 1024 == 0), 4 elems/thread.
// ---------------------------------------------------------------------------
__global__ __launch_bounds__(256) void cvt_f32_bf16(
    const float* __restrict__ in, ushort_t* __restrict__ out) {
  const int i = (blockIdx.x * 256 + threadIdx.x) * 4;
  const float4 v = *(const float4*)(in + i);
  union { ushort_t u[4]; uint2 q; } o;
  o.u[0] = f2bf(v.x); o.u[1] = f2bf(v.y);
  o.u[2] = f2bf(v.z); o.u[3] = f2bf(v.w);
  *(uint2*)(out + i) = o.q;
}

// ---------------------------------------------------------------------------
// MFMA NT GEMM: C[M][N] = A[M][K] * BT[N][K]^T (+bias).  (round-5 proven)
// ---------------------------------------------------------------------------
template <typename TA, typename TC>
__global__ __launch_bounds__(256) void gemm_mfma_nt(
    const TA* __restrict__ A, const ushort_t* __restrict__ BT,
    const float* __restrict__ bias, TC* __restrict__ C,
    int M, int N, int K, int has_bias) {
  __shared__ ushort_t lA[8 * 512];
  __shared__ ushort_t lB[8 * 512];
  const int t = threadIdx.x;
  const int m0 = blockIdx.y * 128;
  const int n0 = blockIdx.x * 128;
  const int lane = t & 63;
  const int wm = (t >> 6) >> 1, wn = (t >> 6) & 1;

  f32x4 acc[4][4] = {};

  const int sm = t >> 2;   // 0..63
  const int kq = t & 3;    // 16B chunk within 32-wide K tile

  for (int k0 = 0; k0 < K; k0 += 32) {
#pragma unroll
    for (int h = 0; h < 2; ++h) {
      const int m = h * 64 + sm;  // 0..127
      const int off = (m >> 4) * 512 + (kq * 16 + (m & 15)) * 8;
      const ushort8v av = load8bf(A + (size_t)(m0 + m) * K + k0 + kq * 8);
      *(ushort8v*)&lA[off] = av;
      const ushort8v bv = load8bf(BT + (size_t)(n0 + m) * K + k0 + kq * 8);
      *(ushort8v*)&lB[off] = bv;
    }
    __syncthreads();
    short8v af[4], bf[4];
#pragma unroll
    for (int i = 0; i < 4; ++i) {
      af[i] = *(const short8v*)&lA[(wm * 4 + i) * 512 + lane * 8];
      bf[i] = *(const short8v*)&lB[(wn * 4 + i) * 512 + lane * 8];
    }
#pragma unroll
    for (int i = 0; i < 4; ++i)
#pragma unroll
      for (int j = 0; j < 4; ++j)
        acc[i][j] = __builtin_amdgcn_mfma_f32_16x16x32_bf16(
            af[i], bf[j], acc[i][j], 0, 0, 0);
    __syncthreads();
  }

  const int col = lane & 15, rq = (lane >> 4) * 4;
#pragma unroll
  for (int i = 0; i < 4; ++i) {
    const int mb = m0 + (wm * 4 + i) * 16 + rq;
#pragma unroll
    for (int j = 0; j < 4; ++j) {
      const int nb = n0 + (wn * 4 + j) * 16 + col;
      const float badd = has_bias ? bias[nb] : 0.f;
#pragma unroll
      for (int r = 0; r < 4; ++r)
        storeC(&C[(size_t)(mb + r) * N + nb], acc[i][j][r] + badd);
    }
  }
}

// ---------------------------------------------------------------------------
// KV conv GEMM, MFMA, fused im2col gather, split-K (S=14), 1-D grid 896.
// Block decode: mt = bl%8 (-> same m-tile lands on one XCD under the
// round-robin block->XCD heuristic; its A rows = 3.2 MB bf16, fits 4MB L2),
// nt = (bl/8)%8, kc = bl/64.
// ---------------------------------------------------------------------------
template <typename TA>
__global__ __launch_bounds__(256) void gemm_kv_mfma(
    const TA* __restrict__ x, const ushort_t* __restrict__ WkvT,
    float* __restrict__ C) {
  __shared__ ushort_t lA[8 * 512];
  __shared__ ushort_t lB[8 * 512];
  const int t = threadIdx.x;
  const int bl = blockIdx.x;
  const int m0 = (bl & 7) * 128;
  const int n0 = ((bl >> 3) & 7) * 128;
  const int kbeg = (bl >> 6) * 896;
  const int lane = t & 63;
  const int wm = (t >> 6) >> 1, wn = (t >> 6) & 1;

  f32x4 acc[4][4] = {};

  const int sm = t >> 2;
  const int kq = t & 3;

  for (int k0 = kbeg; k0 < kbeg + 896; k0 += 32) {
#pragma unroll
    for (int h = 0; h < 2; ++h) {
      const int m = h * 64 + sm;
      const int off = (m >> 4) * 512 + (kq * 16 + (m & 15)) * 8;
      const int gm = m0 + m;
      const int b = gm >> 6, ty = (gm >> 3) & 7, tx = gm & 7;
      const int k = k0 + kq * 8;
      const int patch = k >> 8;          // 0..48
      const int c = k & 255;             // 8-aligned
      const int dy = (patch * 37) >> 8;  // exact /7 for patch<49
      const int dx = patch - dy * 7;
      const int pix = b * 3136 + (ty * 7 + dy) * 56 + (tx * 7 + dx);
      const ushort8v av = load8bf(x + (size_t)pix * 256 + c);
      *(ushort8v*)&lA[off] = av;
      const ushort8v bv =
          load8bf(WkvT + (size_t)(n0 + m) * 12544 + k0 + kq * 8);
      *(ushort8v*)&lB[off] = bv;
    }
    __syncthreads();
    short8v af[4], bf[4];
#pragma unroll
    for (int i = 0; i < 4; ++i) {
      af[i] = *(const short8v*)&lA[(wm * 4 + i) * 512 + lane * 8];
      bf[i] = *(const short8v*)&lB[(wn * 4 + i) * 512 + lane * 8];
    }
#pragma unroll
    for (int i = 0; i < 4; ++i)
#pragma unroll
      for (int j = 0; j < 4; ++j)
        acc[i][j] = __builtin_amdgcn_mfma_f32_16x16x32_bf16(
            af[i], bf[j], acc[i][j], 0, 0, 0);
    __syncthreads();
  }

  const int col = lane & 15, rq = (lane >> 4) * 4;
#pragma unroll
  for (int i = 0; i < 4; ++i) {
    const int mb = m0 + (wm * 4 + i) * 16 + rq;
#pragma unroll
    for (int j = 0; j < 4; ++j) {
      const int nb = n0 + (wn * 4 + j) * 16 + col;
#pragma unroll
      for (int r = 0; r < 4; ++r)
        atomicAdd(&C[(size_t)(mb + r) * 1024 + nb], acc[i][j][r]);
    }
  }
}

// ---------------------------------------------------------------------------
// MFMA attention, in-place on bf16 qbuf.  (round-6 proven)
// ---------------------------------------------------------------------------
__global__ __launch_bounds__(256) void attn_mfma(
    ushort_t* __restrict__ qo, const ushort_t* __restrict__ kvb) {
  __shared__ ushort_t VT[64][72];      // [d][key], 72-short rows (16B-aligned)
  __shared__ ushort_t P[4][64][72];    // per-wave [query][key]
  const int t = threadIdx.x;
  const int lane = t & 63;
  const int w = t >> 6;
  const int bh = blockIdx.y;
  const int b = bh >> 3, h = bh & 7;
  const ushort_t* kvp = kvb + (size_t)(b * 64) * 1024 + h * 64;

  for (int i = t; i < 512; i += 256) {
    const int key = i >> 3, d0 = (i & 7) * 8;
    const ushort8v v = *(const ushort8v*)(kvp + (size_t)key * 1024 + 512 + d0);
#pragma unroll
    for (int jj = 0; jj < 8; ++jj) VT[d0 + jj][key] = v[jj];
  }
  __syncthreads();

  const int q0_raw = blockIdx.x * 256 + w * 64;
  const bool valid = q0_raw < 3136;
  const int q0 = valid ? q0_raw : 3072;  // clamped redundant compute, no store
  const size_t qbase = ((size_t)b * 3136 + q0) * 512 + h * 64;

  const int lm = lane & 15, quad = lane >> 4;

  short8v qf[4][2], kf[4][2];
#pragma unroll
  for (int i = 0; i < 4; ++i)
#pragma unroll
    for (int s = 0; s < 2; ++s) {
      qf[i][s] = *(const short8v*)(qo + qbase + (size_t)(16 * i + lm) * 512 +
                                   32 * s + quad * 8);
      kf[i][s] = *(const short8v*)(kvp + (size_t)(16 * i + lm) * 1024 +
                                   32 * s + quad * 8);
    }

  f32x4 sa[4][4];
#pragma unroll
  for (int i = 0; i < 4; ++i)
#pragma unroll
    for (int j = 0; j < 4; ++j) {
      f32x4 z = {};
      z = __builtin_amdgcn_mfma_f32_16x16x32_bf16(qf[i][0], kf[j][0], z, 0, 0, 0);
      sa[i][j] = __builtin_amdgcn_mfma_f32_16x16x32_bf16(qf[i][1], kf[j][1], z, 0, 0, 0);
    }

  float l[4][4];
#pragma unroll
  for (int i = 0; i < 4; ++i)
#pragma unroll
    for (int r = 0; r < 4; ++r) {
      float m = fmaxf(fmaxf(sa[i][0][r], sa[i][1][r]),
                      fmaxf(sa[i][2][r], sa[i][3][r]));
#pragma unroll
      for (int off = 1; off < 16; off <<= 1) m = fmaxf(m, __shfl_xor(m, off));
      float sum = 0.f;
#pragma unroll
      for (int j = 0; j < 4; ++j) {
        const float p = __expf(0.125f * (sa[i][j][r] - m));
        sa[i][j][r] = p;
        sum += p;
      }
#pragma unroll
      for (int off = 1; off < 16; off <<= 1) sum += __shfl_xor(sum, off);
      l[i][r] = sum;
    }

#pragma unroll
  for (int i = 0; i < 4; ++i) {
    const int row = 16 * i + quad * 4;
#pragma unroll
    for (int j = 0; j < 4; ++j) {
      const int col = 16 * j + lm;
#pragma unroll
      for (int r = 0; r < 4; ++r) P[w][row + r][col] = f2bf(sa[i][j][r]);
    }
  }
  __syncthreads();

  short8v vf[4][2];
#pragma unroll
  for (int jn = 0; jn < 4; ++jn)
#pragma unroll
    for (int s2 = 0; s2 < 2; ++s2)
      vf[jn][s2] = *(const short8v*)&VT[16 * jn + lm][32 * s2 + quad * 8];

  f32x4 oa[4][4];
#pragma unroll
  for (int i = 0; i < 4; ++i) {
    const short8v pf0 = *(const short8v*)&P[w][16 * i + lm][quad * 8];
    const short8v pf1 = *(const short8v*)&P[w][16 * i + lm][32 + quad * 8];
#pragma unroll
    for (int jn = 0; jn < 4; ++jn) {
      f32x4 z = {};
      z = __builtin_amdgcn_mfma_f32_16x16x32_bf16(pf0, vf[jn][0], z, 0, 0, 0);
      oa[i][jn] = __builtin_amdgcn_mfma_f32_16x16x32_bf16(pf1, vf[jn][1], z, 0, 0, 0);
    }
  }

  if (valid) {
#pragma unroll
    for (int i = 0; i < 4; ++i) {
#pragma unroll
      for (int r = 0; r < 4; ++r) {
        const float inv = 1.f / l[i][r];
        const size_t rowoff = qbase + (size_t)(16 * i + quad * 4 + r) * 512;
#pragma unroll
        for (int jn = 0; jn < 4; ++jn)
          qo[rowoff + 16 * jn + lm] = f2bf(oa[i][jn][r] * inv);
      }
    }
  }
}

// ---------------------------------------------------------------------------
// Workspace (bytes), preferred layout total 109,576,192:
//   qbuf  @ 0        : 50176*512*2  = 51,380,224  bf16 (q, then attn out)
//   kvbuf @ 51380224 : 1024*1024*4  =  4,194,304  fp32 (atomic split-K)
//   WkvT  @ 55574528 : 1024*12544*2 = 25,690,112  bf16
//   WqT   @ 81264640 : 512*256*2    =     262,144 bf16
//   WoT   @ 81526784 : 256*512*2    =     262,144 bf16
//   kvbf  @ 81788928 : 1024*1024*2  =  2,097,152  bf16
//   xbf   @ 83886080 : 12845056*2   = 25,690,112  bf16   (if ws allows)
// Fallback (< 110 MB): round-6 path (fp32 x with inline cvt), proven.
// ---------------------------------------------------------------------------
extern "C" void kernel_launch(void* const* d_in, const int* in_sizes, int n_in,
                              void* d_out, int out_size, void* d_ws,
                              size_t ws_size, hipStream_t stream) {
  const float* x = (const float*)d_in[0];
  const float* Wq = (const float*)d_in[1];
  const float* Wkv = (const float*)d_in[2];
  const float* Wo = (const float*)d_in[3];
  const float* bo = (const float*)d_in[4];
  float* out = (float*)d_out;

  char* ws = (char*)d_ws;
  ushort_t* qbuf = (ushort_t*)(ws);
  float* kvbuf = (float*)(ws + 51380224);
  ushort_t* WkvT = (ushort_t*)(ws + 55574528);
  ushort_t* WqT = (ushort_t*)(ws + 81264640);
  ushort_t* WoT = (ushort_t*)(ws + 81526784);
  ushort_t* kvbf = (ushort_t*)(ws + 81788928);
  ushort_t* xbf = (ushort_t*)(ws + 83886080);
  const bool use_xbf = ws_size >= 109576192u;  // constant per session

  // 0) weight transposes + bf16 cvt; kvbuf zero for atomic split-K
  hipLaunchKernelGGL(transpose_cvt, dim3(16, 8), dim3(256), 0, stream, Wq, WqT,
                     256, 512);
  hipLaunchKernelGGL(transpose_cvt, dim3(32, 392), dim3(256), 0, stream, Wkv,
                     WkvT, 12544, 1024);
  hipLaunchKernelGGL(transpose_cvt, dim3(8, 16), dim3(256), 0, stream, Wo, WoT,
                     512, 256);
  hipMemsetAsync(kvbuf, 0, 1024 * 1024 * 4, stream);

  if (use_xbf) {
    // 0b) x -> bf16 once (12,845,056 elems, 4/thread)
    hipLaunchKernelGGL(cvt_f32_bf16, dim3(12544), dim3(256), 0, stream, x,
                       xbf);
    // 1) Q projection from bf16 x
    hipLaunchKernelGGL((gemm_mfma_nt<ushort_t, ushort_t>), dim3(4, 392),
                       dim3(256), 0, stream, xbf, WqT, (const float*)nullptr,
                       qbuf, 50176, 512, 256, 0);
    // 2) KV conv GEMM from bf16 x, split-K=14, XCD-swizzled 1-D grid
    hipLaunchKernelGGL((gemm_kv_mfma<ushort_t>), dim3(896), dim3(256), 0,
                       stream, xbf, WkvT, kvbuf);
  } else {
    hipLaunchKernelGGL((gemm_mfma_nt<float, ushort_t>), dim3(4, 392),
                       dim3(256), 0, stream, x, WqT, (const float*)nullptr,
                       qbuf, 50176, 512, 256, 0);
    hipLaunchKernelGGL((gemm_kv_mfma<float>), dim3(896), dim3(256), 0, stream,
                       x, WkvT, kvbuf);
  }
  hipLaunchKernelGGL(cvt_f32_bf16, dim3(1024), dim3(256), 0, stream, kvbuf,
                     kvbf);
  // 3) MFMA attention, in-place on qbuf
  hipLaunchKernelGGL(attn_mfma, dim3(13, 128), dim3(256), 0, stream, qbuf,
                     kvbf);
  // 4) output projection + bias: [50176,512] x [512,256] -> fp32 out
  hipLaunchKernelGGL((gemm_mfma_nt<ushort_t, float>), dim3(2, 392), dim3(256),
                     0, stream, qbuf, WoT, bo, out, 50176, 256, 512, 1);
}